// Round 8
// baseline (1617.932 us; speedup 1.0000x reference)
//
#include <hip/hip_runtime.h>
#include <hip/hip_bf16.h>

// LSTM_Sequence_Prediction — MI355X, round 16.
// R13/R15 (tagged-word exchange) failed identically (absmax 468, NaN,
// deterministic): the poll loop's 24 split load-asm blocks + separate drain
// asm leave a window where the register allocator may copy/spill in-flight
// load destination VGPRs (LLVM does not track loads issued inside opaque
// asm). Fix: ONE asm block that issues 8 global_load_dwordx4 AND the
// s_waitcnt vmcnt(0), with early-clobber outputs — the load+wait window is
// atomic w.r.t. the compiler. Poll = 3 passes x 8 int4; matched entries are
// LDS-written at first match (first match is provably generation t).
// Everything else (tagged 8B fire-and-forget stores, spin-cap hang-proofing,
// R12-verbatim decoder/lstm_step/head/cvt) is unchanged.

constexpr int NB = 64;    // batch
constexpr int NH = 768;   // hidden
constexpr int NF = 256;   // features
constexpr int NS = 256;   // seq len
constexpr int NT = 32;    // target len
constexpr int ENC_BLOCKS = 96;   // 48 unit-tiles x 2 batch halves
constexpr int DEC_BLOCKS = 48;   // 768 units / 16
constexpr size_t HXBUF = 196608; // one tagged exchange buffer: 64 x 384 x 8 B

typedef short bf16x8 __attribute__((ext_vector_type(8)));
typedef float f32x4 __attribute__((ext_vector_type(4)));

__device__ __forceinline__ float sigm(float x) { return 1.f / (1.f + expf(-x)); }

// LLC-direct (coherent) accesses: sc0 sc1 bypass L1 and the non-coherent XCD L2.
__device__ __forceinline__ int4 ld_i4_cohere(const int4* p) {
    int4 v;
    asm volatile("global_load_dwordx4 %0, %1, off sc0 sc1" : "=v"(v) : "v"(p));
    return v;   // NOT ready until vm_drain()!
}
__device__ __forceinline__ int ld_i1_cohere_sync(const int* p) {
    int v;
    asm volatile("global_load_dword %0, %1, off sc0 sc1\n\ts_waitcnt vmcnt(0)"
                 : "=v"(v) : "v"(p) : "memory");
    return v;
}
__device__ __forceinline__ void st_i1_cohere(int* p, int v) {
    asm volatile("global_store_dword %0, %1, off sc0 sc1" :: "v"(p), "v"(v) : "memory");
}
// single 8-byte store: data dword + tag dword land in one transaction
__device__ __forceinline__ void st_i2_cohere(void* p, int2 v) {
    asm volatile("global_store_dwordx2 %0, %1, off sc0 sc1" :: "v"(p), "v"(v) : "memory");
}
__device__ __forceinline__ void vm_drain() {
    asm volatile("s_waitcnt vmcnt(0)" ::: "memory");
    __builtin_amdgcn_sched_barrier(0);
}

// 8 coherent dwordx4 loads + waitcnt in ONE asm block: the in-flight window
// is invisible to the compiler (no RA copies/spills of in-flight dests).
__device__ __forceinline__ void ld8_i4_cohere_sync(
    const int4* p0, const int4* p1, const int4* p2, const int4* p3,
    const int4* p4, const int4* p5, const int4* p6, const int4* p7,
    int4& w0, int4& w1, int4& w2, int4& w3,
    int4& w4, int4& w5, int4& w6, int4& w7)
{
    asm volatile(
        "global_load_dwordx4 %0, %8, off sc0 sc1\n\t"
        "global_load_dwordx4 %1, %9, off sc0 sc1\n\t"
        "global_load_dwordx4 %2, %10, off sc0 sc1\n\t"
        "global_load_dwordx4 %3, %11, off sc0 sc1\n\t"
        "global_load_dwordx4 %4, %12, off sc0 sc1\n\t"
        "global_load_dwordx4 %5, %13, off sc0 sc1\n\t"
        "global_load_dwordx4 %6, %14, off sc0 sc1\n\t"
        "global_load_dwordx4 %7, %15, off sc0 sc1\n\t"
        "s_waitcnt vmcnt(0)"
        : "=&v"(w0), "=&v"(w1), "=&v"(w2), "=&v"(w3),
          "=&v"(w4), "=&v"(w5), "=&v"(w6), "=&v"(w7)
        : "v"(p0), "v"(p1), "v"(p2), "v"(p3),
          "v"(p4), "v"(p5), "v"(p6), "v"(p7)
        : "memory");
    __builtin_amdgcn_sched_barrier(0);
}

// LLC flag barrier (decoder only)
__device__ __forceinline__ void arrive(int* slots, int idx, int phase) {
    if (threadIdx.x == 0) st_i1_cohere(slots + idx * 16, phase);
}
__device__ __forceinline__ void wait_all(int* slots, int phase, int nb) {
    if (threadIdx.x < nb) {
        const int* p = slots + threadIdx.x * 16;
        while (ld_i1_cohere_sync(p) < phase) __builtin_amdgcn_s_sleep(1);
    }
    __syncthreads();
}

// Fused fp32 -> bf16 conversion for all four regions (dst contiguous in ws).
__global__ __launch_bounds__(256) void cvt_all(
    const float* __restrict__ s0,   //       4,194,304 el (x)
    const float* __restrict__ s1,   //         786,432 el (e_Wih0)
    const float* __restrict__ s2,   //       2,359,296 el (e_Whh0)
    const float* __restrict__ s3,   //       4,718,592 el (e_Wih[0..1])
    __hip_bfloat16* __restrict__ d) // 12,058,624 el total
{
    const int i = (blockIdx.x * 256 + threadIdx.x) * 4;
    const float* s; int off;
    if (i < 4194304)      { s = s0; off = 0; }
    else if (i < 4980736) { s = s1; off = 4194304; }
    else if (i < 7340032) { s = s2; off = 4980736; }
    else                  { s = s3; off = 7340032; }
    const float4 v = *(const float4*)(s + (i - off));
    d[i]     = __float2bfloat16(v.x);
    d[i + 1] = __float2bfloat16(v.y);
    d[i + 2] = __float2bfloat16(v.z);
    d[i + 3] = __float2bfloat16(v.w);
}

// Fused persistent kernel.
//   blocks 0..95   : encoder layer 0, tagged-word LLC exchange.
//   blocks 96..143 : decoder (verbatim R12), independent, hides under enc.
__global__ __launch_bounds__(256, 1) void enc_dec_persist(
    const __hip_bfloat16* __restrict__ xb,    // NS x NB x NF bf16 (cached)
    const __hip_bfloat16* __restrict__ Wx,    // 4H x NF bf16 (cached)
    const __hip_bfloat16* __restrict__ Wh,    // 4H x NH bf16 (cached)
    const float* __restrict__ bih, const float* __restrict__ bhh,
    char* __restrict__ hxt,                   // 2 x HXBUF tagged exchange (zeroed)
    __hip_bfloat16* __restrict__ hfin,        // NB x NH bf16 final h (for lstm_step)
    float* __restrict__ enc0,                 // NB x NH fp32 (final h out)
    const float* __restrict__ dW,             // decoder layer-2 Wih (fp32)
    const float* __restrict__ dbih, const float* __restrict__ dbhh,
    float* __restrict__ hd0, float* __restrict__ hd1,
    float* __restrict__ hall, int* dslots)    // dec: 48 x 16 ints (zeroed)
{
    // combined static LDS: 49,664 + 8,704 + 256 + 3,072 = 61,696 B (< 64 KiB)
    __shared__ int   hst[32 * 388];           // enc: staged h (+4-int pad/row)
    __shared__ float gbuf[4][32][17];         // enc: gate staging
    __shared__ float lbias[64];               // enc: fused bias
    __shared__ float hstD[768];               // dec: staged h

    const int tid = threadIdx.x;

    if (blockIdx.x >= ENC_BLOCKS) {
        // ================= decoder path (verbatim R12) =================
        const int dbid = blockIdx.x - ENC_BLOCKS;
        const int ul = tid >> 4;
        const int j  = tid & 15;
        const int u  = dbid * 16 + ul;
        const float* Wi = dW + (size_t)u * NH;
        const float* Wg = dW + (size_t)(2 * NH + u) * NH;
        const float* Wo = dW + (size_t)(3 * NH + u) * NH;
        const float bi = dbih[u]          + dbhh[u];
        const float bg = dbih[2 * NH + u] + dbhh[2 * NH + u];
        const float bo = dbih[3 * NH + u] + dbhh[3 * NH + u];

        for (int t = 0; t < NT; ++t) {
            const float* hin = (t & 1) ? hd1 : hd0;
            float* hout      = (t & 1) ? hd0 : hd1;
            if (t > 0) wait_all(dslots, t, DEC_BLOCKS);
            if (tid < 192) {
                int4 v = ld_i4_cohere((const int4*)hin + tid);
                vm_drain();
                ((int4*)hstD)[tid] = v;
            }
            __syncthreads();
            float ai = 0.f, ag = 0.f, ao = 0.f;
            for (int k = j; k < NH; k += 16) {
                const float hv = hstD[k];
                ai += hv * Wi[k];
                ag += hv * Wg[k];
                ao += hv * Wo[k];
            }
            #pragma unroll
            for (int off = 8; off > 0; off >>= 1) {
                ai += __shfl_xor(ai, off, 16);
                ag += __shfl_xor(ag, off, 16);
                ao += __shfl_xor(ao, off, 16);
            }
            if (j == 0) {
                const float cn = sigm(ai + bi) * tanhf(ag + bg);
                const float hn = sigm(ao + bo) * tanhf(cn);
                hall[(size_t)t * NH + u] = hn;         // plain (read post-dispatch)
                if (t < NT - 1)
                    st_i1_cohere((int*)(hout + u), __float_as_int(hn));
            }
            if (t < NT - 1) {
                vm_drain();
                __syncthreads();
                arrive(dslots, dbid, t + 1);
            }
        }
        return;
    }

    // ================= encoder path: tagged-word exchange =================
    const int bu = blockIdx.x % (NH / 16);    // unit tile (48)
    const int bm = blockIdx.x / (NH / 16);    // batch half (2)
    const int u0 = bu * 16;
    const int g = tid >> 6;                   // wave index == gate index
    const int lane = tid & 63;
    const int r = lane & 15;
    const int q = lane >> 4;
    const int row0 = bm * 32 + r;
    const int row1 = row0 + 16;

    // weight B-fragments (ordinary cached loads)
    const size_t wrow = (size_t)(g * NH + u0 + r);
    bf16x8 wx[8], wh[24];
    #pragma unroll
    for (int c = 0; c < 8; ++c)
        wx[c] = *(const bf16x8*)(Wx + wrow * NF + c * 32 + q * 8);
    #pragma unroll
    for (int c = 0; c < 24; ++c)
        wh[c] = *(const bf16x8*)(Wh + wrow * NH + c * 32 + q * 8);

    if (tid < 64)
        lbias[tid] = bih[(tid >> 4) * NH + u0 + (tid & 15)]
                   + bhh[(tid >> 4) * NH + u0 + (tid & 15)];
    __syncthreads();

    float cst[2] = {0.f, 0.f};                // cell state, 2 cells/thread

    // epilogue store geometry: thread (rowl = tid>>3, pair = tid&7) packs
    // units (u0 + 2*pair, u0 + 2*pair + 1) for batch row bm*32+rowl into one
    // tagged 8B word at tagged-int2 index b*384 + bu*8 + pair.
    const int rowl = tid >> 3, pair = tid & 7;
    const int bsto = bm * 32 + rowl;
    char* const slot_even = hxt + HXBUF + ((size_t)bsto * 384 + bu * 8 + pair) * 8;
    char* const slot_odd  = hxt +         ((size_t)bsto * 384 + bu * 8 + pair) * 8;

    for (int t = 0; t < NS; ++t) {
        const __hip_bfloat16* xt = xb + (size_t)t * NB * NF;

        // ---- x-part (independent of h_t): overlaps stores in flight ----
        f32x4 acc0 = {0.f, 0.f, 0.f, 0.f};
        f32x4 acc1 = {0.f, 0.f, 0.f, 0.f};
        #pragma unroll
        for (int c = 0; c < 8; ++c) {
            const bf16x8 a0 = *(const bf16x8*)(xt + (size_t)row0 * NF + c * 32 + q * 8);
            const bf16x8 a1 = *(const bf16x8*)(xt + (size_t)row1 * NF + c * 32 + q * 8);
            acc0 = __builtin_amdgcn_mfma_f32_16x16x32_bf16(a0, wx[c], acc0, 0, 0, 0);
            acc1 = __builtin_amdgcn_mfma_f32_16x16x32_bf16(a1, wx[c], acc1, 0, 0, 0);
        }

        // ---- poll + stage: 3 passes x 8 tagged int4s, sync mega-loads ----
        {
            const int4* src = (const int4*)(hxt + (size_t)(t & 1) * HXBUF)
                            + bm * 6144 + tid;
            #pragma unroll
            for (int pass = 0; pass < 3; ++pass) {
                const int base = pass * 8;
                unsigned done = 0;
                int spin = 0;
                while (done != 0xFFu && ++spin < 8192) {
                    int4 w0, w1, w2, w3, w4, w5, w6, w7;
                    ld8_i4_cohere_sync(
                        src + (base + 0) * 256, src + (base + 1) * 256,
                        src + (base + 2) * 256, src + (base + 3) * 256,
                        src + (base + 4) * 256, src + (base + 5) * 256,
                        src + (base + 6) * 256, src + (base + 7) * 256,
                        w0, w1, w2, w3, w4, w5, w6, w7);
                    const int4 wa[8] = {w0, w1, w2, w3, w4, w5, w6, w7};
                    #pragma unroll
                    for (int i = 0; i < 8; ++i) {
                        if (!(done & (1u << i)) && wa[i].y == t && wa[i].w == t) {
                            // first match is provably generation t: write now
                            const int f  = ((base + i) * 256 + tid) * 2;
                            const int rw = f / 384, pc = f % 384;
                            *(int2*)((char*)hst + rw * 1552 + pc * 4)
                                = make_int2(wa[i].x, wa[i].z);
                            done |= 1u << i;
                        }
                    }
                }
            }
        }
        __syncthreads();

        // ---- h-part MFMAs from LDS ----
        #pragma unroll
        for (int c = 0; c < 24; ++c) {
            const bf16x8 a0 = *(const bf16x8*)((const short*)hst + r * 776 + c * 32 + q * 8);
            const bf16x8 a1 = *(const bf16x8*)((const short*)hst + (r + 16) * 776 + c * 32 + q * 8);
            acc0 = __builtin_amdgcn_mfma_f32_16x16x32_bf16(a0, wh[c], acc0, 0, 0, 0);
            acc1 = __builtin_amdgcn_mfma_f32_16x16x32_bf16(a1, wh[c], acc1, 0, 0, 0);
        }

        // C/D layout: col = lane&15 (unit), row = (lane>>4)*4 + reg
        #pragma unroll
        for (int i = 0; i < 4; ++i) {
            gbuf[g][q * 4 + i][r]      = acc0[i];
            gbuf[g][16 + q * 4 + i][r] = acc1[i];
        }
        __syncthreads();

        // ---- fused cell epilogue: 2 adjacent units per thread ----
        {
            const int ua = pair * 2;
            float h2[2];
            #pragma unroll
            for (int e = 0; e < 2; ++e) {
                const int ul = ua + e;
                const float pi = gbuf[0][rowl][ul] + lbias[ul];
                const float pf = gbuf[1][rowl][ul] + lbias[16 + ul];
                const float pg = gbuf[2][rowl][ul] + lbias[32 + ul];
                const float po = gbuf[3][rowl][ul] + lbias[48 + ul];
                const float cn = sigm(pf) * cst[e] + sigm(pi) * tanhf(pg);
                h2[e] = sigm(po) * tanhf(cn);
                cst[e] = cn;
            }
            if (t == NS - 1) {
                enc0[(size_t)bsto * NH + u0 + ua]     = h2[0];
                enc0[(size_t)bsto * NH + u0 + ua + 1] = h2[1];
                hfin[(size_t)bsto * NH + u0 + ua]     = __float2bfloat16(h2[0]);
                hfin[(size_t)bsto * NH + u0 + ua + 1] = __float2bfloat16(h2[1]);
            } else {
                union { __hip_bfloat16 b16; unsigned short s; } c0, c1;
                c0.b16 = __float2bfloat16(h2[0]);
                c1.b16 = __float2bfloat16(h2[1]);
                const int pv = (int)c0.s | ((int)c1.s << 16);
                // single 8B tagged store; fire-and-forget (no drain, no flag)
                st_i2_cohere((t & 1) ? slot_odd : slot_even, make_int2(pv, t + 1));
            }
        }
        // no post-store barrier: hst/gbuf reuse is protected by the two
        // __syncthreads above; inter-block ordering by the tag protocol.
    }
}

// One-shot LSTM step (encoder layers 1..2): gates = xin@Wx^T + b; c_prev = 0.
template<int KX, int KH>
__global__ __launch_bounds__(256) void lstm_step(
    const __hip_bfloat16* __restrict__ xin,
    const __hip_bfloat16* __restrict__ hin,
    const __hip_bfloat16* __restrict__ Wx,
    const __hip_bfloat16* __restrict__ Wh,
    const float* __restrict__ bih, const float* __restrict__ bhh,
    const float* __restrict__ c_in,
    __hip_bfloat16* __restrict__ h_bf,
    float* __restrict__ h_f32,
    float* __restrict__ c_out)
{
    constexpr int K = KX + KH;
    constexpr int NCH = K / 32;
    const int bu = blockIdx.x % (NH / 16);
    const int bm = blockIdx.x / (NH / 16);
    const int u0 = bu * 16;
    const int tid = threadIdx.x;
    const int g = tid >> 6;
    const int lane = tid & 63;
    const int r = lane & 15;
    const int q = lane >> 4;

    f32x4 acc0 = {0.f, 0.f, 0.f, 0.f};
    f32x4 acc1 = {0.f, 0.f, 0.f, 0.f};
    const int row0 = bm * 32 + r;
    const int row1 = row0 + 16;
    const long wr = (long)(g * NH + u0 + r);

    #pragma unroll
    for (int c = 0; c < NCH; ++c) {
        const int k0 = c * 32;
        bf16x8 a0, a1, bfrag;
        if (k0 < KX) {
            const int kk = k0 + q * 8;
            a0 = *(const bf16x8*)(xin + (long)row0 * KX + kk);
            a1 = *(const bf16x8*)(xin + (long)row1 * KX + kk);
            bfrag = *(const bf16x8*)(Wx + wr * KX + kk);
        } else {
            const int kk = (k0 - KX) + q * 8;
            a0 = *(const bf16x8*)(hin + (long)row0 * KH + kk);
            a1 = *(const bf16x8*)(hin + (long)row1 * KH + kk);
            bfrag = *(const bf16x8*)(Wh + wr * KH + kk);
        }
        acc0 = __builtin_amdgcn_mfma_f32_16x16x32_bf16(a0, bfrag, acc0, 0, 0, 0);
        acc1 = __builtin_amdgcn_mfma_f32_16x16x32_bf16(a1, bfrag, acc1, 0, 0, 0);
    }

    __shared__ float gbuf[4][32][17];
    #pragma unroll
    for (int i = 0; i < 4; ++i) {
        gbuf[g][q * 4 + i][r]      = acc0[i];
        gbuf[g][16 + q * 4 + i][r] = acc1[i];
    }
    __syncthreads();

    #pragma unroll
    for (int i = 0; i < 2; ++i) {
        const int idx = tid + i * 256;
        const int bl = idx >> 4;
        const int u  = idx & 15;
        const int gu = u0 + u;
        const int b  = bm * 32 + bl;
        const float pi = gbuf[0][bl][u] + bih[gu]          + bhh[gu];
        const float pf = gbuf[1][bl][u] + bih[NH + gu]     + bhh[NH + gu];
        const float pg = gbuf[2][bl][u] + bih[2 * NH + gu] + bhh[2 * NH + gu];
        const float po = gbuf[3][bl][u] + bih[3 * NH + gu] + bhh[3 * NH + gu];
        const float cp = c_in ? c_in[(long)b * NH + gu] : 0.f;
        const float cn = sigm(pf) * cp + sigm(pi) * tanhf(pg);
        const float hn = sigm(po) * tanhf(cn);
        if (c_out) c_out[(long)b * NH + gu] = cn;
        if (h_f32) h_f32[(long)b * NH + gu] = hn;
        h_bf[(long)b * NH + gu] = __float2bfloat16(hn);
    }
}

// Head: out[t,b,f] = hdec_all[t]@lin_W^T + lin_b, broadcast over batch.
__global__ __launch_bounds__(256) void head_kernel(
    const float* __restrict__ hall,
    const float* __restrict__ lw,
    const float* __restrict__ lb,
    float* __restrict__ out)
{
    const int t = blockIdx.x;
    const int f = threadIdx.x;
    const float* h = hall + (size_t)t * NH;
    const float4* wrow = (const float4*)(lw + (size_t)f * NH);
    float acc = 0.f;
    for (int k4 = 0; k4 < NH / 4; ++k4) {
        const float4 w = wrow[k4];
        acc += h[k4 * 4]     * w.x;
        acc += h[k4 * 4 + 1] * w.y;
        acc += h[k4 * 4 + 2] * w.z;
        acc += h[k4 * 4 + 3] * w.w;
    }
    acc += lb[f];
    float* o = out + (size_t)t * NB * NF + f;
    for (int b = 0; b < NB; ++b) o[(size_t)b * NF] = acc;
}

extern "C" void kernel_launch(void* const* d_in, const int* in_sizes, int n_in,
                              void* d_out, int out_size, void* d_ws, size_t ws_size,
                              hipStream_t stream) {
    (void)in_sizes; (void)n_in; (void)out_size; (void)ws_size;
    const float* x     = (const float*)d_in[0];
    const float* eWih0 = (const float*)d_in[1];
    const float* eWhh0 = (const float*)d_in[2];
    const float* ebih0 = (const float*)d_in[3];
    const float* ebhh0 = (const float*)d_in[4];
    const float* eWih  = (const float*)d_in[5];
    // d_in[6] = e_Whh : provably unused
    const float* ebih  = (const float*)d_in[7];
    const float* ebhh  = (const float*)d_in[8];
    const float* dWih  = (const float*)d_in[9];
    // d_in[10] = d_Whh : provably unused
    const float* dbih  = (const float*)d_in[11];
    const float* dbhh  = (const float*)d_in[12];
    const float* linW  = (const float*)d_in[13];
    const float* linb  = (const float*)d_in[14];
    float* out = (float*)d_out;

    // ---- workspace layout (bytes) ----
    char* ws = (char*)d_ws;
    __hip_bfloat16* xb   = (__hip_bfloat16*)(ws);              // 8,388,608 B
    __hip_bfloat16* W0x  = (__hip_bfloat16*)(ws +  8388608);   // 1,572,864 B
    __hip_bfloat16* W0h  = (__hip_bfloat16*)(ws +  9961472);   // 4,718,592 B
    __hip_bfloat16* eW12 = (__hip_bfloat16*)(ws + 14680064);   // 9,437,184 B
    char* hxt  = ws + 24117248;                                // 2 x 196,608 B tagged
    __hip_bfloat16* hfin = (__hip_bfloat16*)(ws + 24510464);   // 98,304 B final h bf16
    __hip_bfloat16* hmid = (__hip_bfloat16*)(ws + 24608768);   // 98,304 B lstm_step scratch
    float* hd0  = (float*)(ws + 24707072);                     // 3,072 B
    float* hd1  = (float*)(ws + 24710144);                     // 3,072 B
    float* hall = (float*)(ws + 24713216);                     // 98,304 B
    int* bar    = (int*)(ws + 24811520);                       // 16,384 B
    int* dec_slots = bar;                                      // 48 x 64 B

    // zero tagged exchange (both buffers: kills replay-stale tags), dec state,
    // barrier slots (ws poisoned 0xAA each call)
    (void)hipMemsetAsync(hxt, 0, 2 * HXBUF, stream);
    (void)hipMemsetAsync(hd0, 0, (size_t)NH * 4, stream);
    (void)hipMemsetAsync(bar, 0, 16384, stream);

    // one fused fp32 -> bf16 conversion kernel (dst contiguous at ws+0)
    cvt_all<<<12058624 / 1024, 256, 0, stream>>>(x, eWih0, eWhh0, eWih,
                                                 (__hip_bfloat16*)ws);

    float* enc = out + (size_t)NT * NB * NF;                   // encoder_hidden slab

    // fused encoder layer 0 + decoder, one persistent launch
    const float* W2 = dWih + (size_t)2 * 4 * NH * NH;
    enc_dec_persist<<<ENC_BLOCKS + DEC_BLOCKS, 256, 0, stream>>>(
        xb, W0x, W0h, ebih0, ebhh0, hxt, hfin, enc,
        W2, dbih + 2 * 4 * NH, dbhh + 2 * 4 * NH, hd0, hd1, hall, dec_slots);

    // encoder layers 1..2
    lstm_step<NH, 0><<<96, 256, 0, stream>>>(
        hfin, nullptr, eW12, nullptr, ebih, ebhh,
        nullptr, hmid, enc + NB * NH, nullptr);
    lstm_step<NH, 0><<<96, 256, 0, stream>>>(
        hmid, nullptr, eW12 + (size_t)4 * NH * NH, nullptr,
        ebih + 4 * NH, ebhh + 4 * NH,
        nullptr, hfin, enc + 2 * (size_t)NB * NH, nullptr);

    // head + batch broadcast
    head_kernel<<<NT, NF, 0, stream>>>(hall, linW, linb, out);
}